// Round 21
// baseline (1093.976 us; speedup 1.0000x reference)
//
#include <hip/hip_runtime.h>

// Viterbi decode (CRF): B=128, T=4096, L=64.
// Outputs: score[B] (f32), path[B][T] (written as float labels).
constexpr int kB = 128;
constexpr int kT = 4096;
constexpr int kL = 64;
constexpr int kSeg = 64;     // number of backtrace segments
constexpr int kSegLen = 64;  // rows per segment (last segment has 63)
constexpr float kNeg = -10000.0f;

typedef float f32x4 __attribute__((ext_vector_type(4)));

#if __has_builtin(__builtin_amdgcn_permlane16_swap)
#define HAS_PLX 1
#else
#define HAS_PLX 0
#endif

// ---------------- K1 forward: 8-wave cooperative step -----------------------
// Block = 512 threads (8 waves); wave w owns outputs [8w,8w+8); lane octet
// (lane&7 = li, lane>>3 = g) splits j into eighths: j in [8g,8g+8).
// Per lane: 2 ds_read_b128 + 8 adds + 4-op tree -> eighth-partial. Combines
// (all VALU, zero DS round-trips — R20 proved removing DS RTs from the chain
// is THE lever: shfl->pl16 took 919->795):
//   bit5 (i^32): permlane32_swap + fmaxf   [proven exact R16-R20]
//   bit4 (i^16): permlane16_swap + fmaxf   [proven exact R20]
//   bit3 (i^8):  DPP row_ror:8 + fmaxf — within a 16-lane row ror-8 maps
//                p -> p^8 exactly, so fmaxf(m, ror8(m)) is the symmetric
//                pair-max (order-free, same argument as the swaps).
// Runtime verify (2 chained steps, bitwise, block-uniform flag) against a
// __shfl_xor-combines step (HIP-contract semantics); fallback runs that loop.
__device__ __forceinline__ float part8(const float (&tr)[8], const f32x4* dlp) {
  f32x4 v0 = dlp[0], v1 = dlp[1];      // 2x ds_read_b128
  float a0 = tr[0] + v0.x, a1 = tr[1] + v0.y;
  float a2 = tr[2] + v0.z, a3 = tr[3] + v0.w;
  float a4 = tr[4] + v1.x, a5 = tr[5] + v1.y;
  float a6 = tr[6] + v1.z, a7 = tr[7] + v1.w;
  float m0 = fmaxf(fmaxf(a0, a1), a2);   // v_max3
  float m1 = fmaxf(fmaxf(a3, a4), a5);   // v_max3
  float m2 = fmaxf(a6, a7);
  return fmaxf(fmaxf(m0, m1), m2);       // v_max3
}

__device__ __forceinline__ float step_shfl8(const float (&tr)[8], const f32x4* dlp,
                                            float fo) {
  float m = part8(tr, dlp);
  m = fmaxf(m, __shfl_xor(m, 32, 64));
  m = fmaxf(m, __shfl_xor(m, 16, 64));
  m = fmaxf(m, __shfl_xor(m, 8, 64));
  return m + fo;
}

#if HAS_PLX
__device__ __forceinline__ float step_pl8(const float (&tr)[8], const f32x4* dlp,
                                          float fo) {
  float m = part8(tr, dlp);
  auto w2 = __builtin_amdgcn_permlane32_swap(__float_as_uint(m), __float_as_uint(m),
                                             false, false);
  m = fmaxf(__uint_as_float(w2[0]), __uint_as_float(w2[1]));   // i ^ 32
  auto w3 = __builtin_amdgcn_permlane16_swap(__float_as_uint(m), __float_as_uint(m),
                                             false, false);
  m = fmaxf(__uint_as_float(w3[0]), __uint_as_float(w3[1]));   // i ^ 16
  int r = __builtin_amdgcn_update_dpp(0, __float_as_int(m), 0x128 /*row_ror:8*/,
                                      0xF, 0xF, true);
  m = fmaxf(m, __int_as_float(r));                             // i ^ 8
  return m + fo;
}
#endif

__global__ __launch_bounds__(512, 1) void fwd_delta(const float* __restrict__ feats,
                                                    const float* __restrict__ trans,
                                                    float* __restrict__ delta) {
  const int tid = threadIdx.x;
  const int w = tid >> 6;          // wave 0..7
  const int lane = tid & 63;
  const int g = lane >> 3;         // j-eighth
  const int li = lane & 7;
  const int o = 8 * w + li;        // output label owned by this lane octet
  const int b = blockIdx.x;
  const size_t kBL = (size_t)kB * kL;

  // tr[k] = trans[o][8g + k], k=0..7 (two float4 loads)
  float tr[8];
  {
    float4 v = *reinterpret_cast<const float4*>(trans + o * kL + 8 * g);
    tr[0] = v.x; tr[1] = v.y; tr[2] = v.z; tr[3] = v.w;
    float4 u = *reinterpret_cast<const float4*>(trans + o * kL + 8 * g + 4);
    tr[4] = u.x; tr[5] = u.y; tr[6] = u.z; tr[7] = u.w;
  }

  __shared__ __align__(16) float dbuf[2][kL];
  __shared__ int okf;
  const f32x4* dlp0 = reinterpret_cast<const f32x4*>(&dbuf[0][8 * g]);
  const f32x4* dlp1 = reinterpret_cast<const f32x4*>(&dbuf[1][8 * g]);

  if (tid == 0) okf = 1;
  if (tid < kL) {
    float dd = (tid == 62) ? 0.0f : kNeg;
    dbuf[0][tid] = dd;
    delta[(size_t)b * kL + tid] = dd;
  }
  __syncthreads();

  const float* fpo = feats + (size_t)b * kT * kL + o;
  float* dro = delta + (size_t)b * kL + o;  // store base; step t at dro[off]

  // LDS-only barrier: own DS ops complete, then s_barrier (R18-R20, exact).
#define LDS_BAR()                                                               \
  {                                                                             \
    asm volatile("s_waitcnt lgkmcnt(0)" ::: "memory");                          \
    __builtin_amdgcn_s_barrier();                                               \
  }

  // ---- verify pl8 vs shfl8: 2 chained steps, bitwise; state-free ----
  {
    float fA = fpo[64 * 1], fB = fpo[64 * 2];
    float d1 = step_shfl8(tr, dlp0, fA);
    if (lane < 8) dbuf[1][o] = d1;
    LDS_BAR();
    float d2 = step_shfl8(tr, dlp1, fB);
    LDS_BAR();  // all reads of dbuf[1] complete before the pl8 trial rewrites
#if HAS_PLX
    float p1 = step_pl8(tr, dlp0, fA);
    if (lane < 8) dbuf[1][o] = p1;
    LDS_BAR();
    float p2 = step_pl8(tr, dlp1, fB);
    LDS_BAR();
    bool wok = __all((__float_as_int(p1) == __float_as_int(d1)) &&
                     (__float_as_int(p2) == __float_as_int(d2))) != 0;
    if (!wok && lane == 0) okf = 0;
#else
    (void)d2;
    if (lane == 0) okf = 0;
#endif
    __syncthreads();
  }
  const bool use8 = (okf != 0);

  // ---- main loop: EXACT R18/R20 structure (in-bounds proven) ----
  // dbuf[0] still holds t=0 (verify wrote only dbuf[1]).
  float f0 = fpo[64 * 1], f1 = fpo[64 * 2], f2 = fpo[64 * 3], f3 = fpo[64 * 4];
  const float* pf = fpo + 64 * 5;
  size_t off = kBL;  // t=1

#define STEP(FN, DLP, WBUF, FV)                                                 \
  {                                                                             \
    float dnew = FN(tr, DLP, FV);                                               \
    if (lane < 8) {                                                             \
      dbuf[WBUF][o] = dnew;                                                     \
      dro[off] = dnew;                                                          \
    }                                                                           \
    off += kBL;                                                                 \
    LDS_BAR();                                                                  \
  }

#if HAS_PLX
  if (use8) {
    for (int it = 0; it < 1022; ++it) {  // steps t=1..4088
      STEP(step_pl8, dlp0, 1, f0) f0 = pf[0];
      STEP(step_pl8, dlp1, 0, f1) f1 = pf[64];
      STEP(step_pl8, dlp0, 1, f2) f2 = pf[128];
      STEP(step_pl8, dlp1, 0, f3) f3 = pf[192];
      pf += 256;
    }
    float g0 = pf[0], g1 = pf[64], g2 = pf[128];  // rows 4093..4095
    STEP(step_pl8, dlp0, 1, f0)   // 4089
    STEP(step_pl8, dlp1, 0, f1)   // 4090
    STEP(step_pl8, dlp0, 1, f2)   // 4091
    STEP(step_pl8, dlp1, 0, f3)   // 4092
    STEP(step_pl8, dlp0, 1, g0)   // 4093
    STEP(step_pl8, dlp1, 0, g1)   // 4094
    STEP(step_pl8, dlp0, 1, g2)   // 4095
  } else
#endif
  {
    for (int it = 0; it < 1022; ++it) {
      STEP(step_shfl8, dlp0, 1, f0) f0 = pf[0];
      STEP(step_shfl8, dlp1, 0, f1) f1 = pf[64];
      STEP(step_shfl8, dlp0, 1, f2) f2 = pf[128];
      STEP(step_shfl8, dlp1, 0, f3) f3 = pf[192];
      pf += 256;
    }
    float g0 = pf[0], g1 = pf[64], g2 = pf[128];
    STEP(step_shfl8, dlp0, 1, f0)
    STEP(step_shfl8, dlp1, 0, f1)
    STEP(step_shfl8, dlp0, 1, f2)
    STEP(step_shfl8, dlp1, 0, f3)
    STEP(step_shfl8, dlp0, 1, g0)
    STEP(step_shfl8, dlp1, 0, g1)
    STEP(step_shfl8, dlp0, 1, g2)
  }
#undef STEP
#undef LDS_BAR
}

// ---------------- K2: recompute backpointers from stored delta --------------
// row r = t*128 + b; delta layout [T][B][L] makes row base = delta + r*64.
__global__ __launch_bounds__(256) void psi_from_delta(const float* __restrict__ delta,
                                                      const float* __restrict__ trans,
                                                      unsigned char* __restrict__ psi) {
  const int lane = threadIdx.x & 63;
  const int w = __builtin_amdgcn_readfirstlane(blockIdx.x * 4 + (threadIdx.x >> 6));
  float tr[kL];
#pragma unroll
  for (int k = 0; k < kL; k += 4) {
    float4 v = *reinterpret_cast<const float4*>(trans + lane * kL + k);
    tr[k] = v.x; tr[k + 1] = v.y; tr[k + 2] = v.z; tr[k + 3] = v.w;
  }
  const int r0 = w * 8;  // 8 rows per wave; grid sized exactly
  for (int rr = 0; rr < 8; ++rr) {
    const int r = r0 + rr;
    const float4* row4 = reinterpret_cast<const float4*>(delta + (size_t)r * kL);
    float bA = -INFINITY, bBv = -INFINITY;
    int iA = 0, iB = 32;
#pragma unroll
    for (int q = 0; q < 8; ++q) {
      float4 dv = row4[q];
      float c; bool g;
      c = tr[4 * q + 0] + dv.x; g = c > bA; bA = g ? c : bA; iA = g ? 4 * q + 0 : iA;
      c = tr[4 * q + 1] + dv.y; g = c > bA; bA = g ? c : bA; iA = g ? 4 * q + 1 : iA;
      c = tr[4 * q + 2] + dv.z; g = c > bA; bA = g ? c : bA; iA = g ? 4 * q + 2 : iA;
      c = tr[4 * q + 3] + dv.w; g = c > bA; bA = g ? c : bA; iA = g ? 4 * q + 3 : iA;
    }
#pragma unroll
    for (int q = 8; q < 16; ++q) {
      float4 dv = row4[q];
      float c; bool g;
      c = tr[4 * q + 0] + dv.x; g = c > bBv; bBv = g ? c : bBv; iB = g ? 4 * q + 0 : iB;
      c = tr[4 * q + 1] + dv.y; g = c > bBv; bBv = g ? c : bBv; iB = g ? 4 * q + 1 : iB;
      c = tr[4 * q + 2] + dv.z; g = c > bBv; bBv = g ? c : bBv; iB = g ? 4 * q + 2 : iB;
      c = tr[4 * q + 3] + dv.w; g = c > bBv; bBv = g ? c : bBv; iB = g ? 4 * q + 3 : iB;
    }
    bool gm = bBv > bA;  // tie -> lower half (first occurrence)
    psi[(size_t)r * kL + lane] = (unsigned char)(gm ? iB : iA);
  }
}

// ---------------- K3: segment composition (in-place psi -> M) ----------------
__global__ __launch_bounds__(256) void seg_compose(unsigned char* psiM,
                                                   unsigned char* __restrict__ C) {
  const int lane = threadIdx.x & 63;
  const int w = blockIdx.x * 4 + (threadIdx.x >> 6);
  const int s = w >> 7;
  const int b = w & 127;
  const int tstart = s * kSegLen;
  const int tend = (tstart + kSegLen < kT) ? tstart + kSegLen : kT - 1;  // last seg: 4095
  const size_t stride = (size_t)kB * kL;
  size_t off = ((size_t)(tend - 1) * kB + b) * kL + lane;
  int m = lane;
  int v = psiM[off];
  for (int t = tend - 1; t > tstart; --t) {
    int vn = psiM[off - stride];          // prefetch next row
    m = __shfl(v, m, 64);                 // m = psi_row[m]
    psiM[off] = (unsigned char)m;         // M[t][b][e] = path[t] | hyp e
    v = vn;
    off -= stride;
  }
  m = __shfl(v, m, 64);
  psiM[off] = (unsigned char)m;
  C[((size_t)s * kB + b) * kL + lane] = (unsigned char)m;  // composed map
}

// ---------------- K4: score, last label, boundary-label scan ----------------
__global__ __launch_bounds__(64) void score_scan(const float* __restrict__ dfin,
                                                 const unsigned char* __restrict__ C,
                                                 int* __restrict__ E,
                                                 float* __restrict__ out) {
  const int b = blockIdx.x;
  const int i = threadIdx.x;
  float d = dfin[(size_t)b * kL + i];
  float m = d;
#pragma unroll
  for (int off = 32; off; off >>= 1) m = fmaxf(m, __shfl_xor(m, off, 64));
  unsigned long long msk = __ballot(d == m);
  int ll = __ffsll(msk) - 1;  // first (lowest) argmax lane
  if (i == 0) {
    out[b] = m;
    out[kB + (size_t)b * kT + (kT - 1)] = (float)ll;
    int lbl = ll;
    for (int s = kSeg - 1; s >= 0; --s) {
      E[s * kB + b] = lbl;                              // label at t_end(s)
      lbl = C[((size_t)s * kB + b) * kL + lbl];         // -> label at t_start(s)
    }
  }
}

// ---------------- K5: parallel path gather ----------------
__global__ __launch_bounds__(256) void path_fill(const unsigned char* __restrict__ M,
                                                 const int* __restrict__ E,
                                                 float* __restrict__ out) {
  const int n = blockIdx.x * 256 + threadIdx.x;  // n = b*4096 + t
  const int b = n >> 12;
  const int t = n & (kT - 1);
  if (t == kT - 1) return;  // written by score_scan
  const int e = E[(t >> 6) * kB + b];
  const unsigned char lab = M[((size_t)t * kB + b) * kL + e];
  out[kB + (size_t)b * kT + t] = (float)lab;
}

extern "C" void kernel_launch(void* const* d_in, const int* in_sizes, int n_in,
                              void* d_out, int out_size, void* d_ws, size_t ws_size,
                              hipStream_t stream) {
  const float* feats = (const float*)d_in[0];
  const float* trans = (const float*)d_in[1];
  float* out = (float*)d_out;
  char* ws = (char*)d_ws;

  const size_t deltaB = (size_t)kT * kB * kL * 4;   // 134,217,728
  const size_t psiB   = (size_t)kT * kB * kL;       //  33,554,432
  const size_t CBy    = (size_t)kSeg * kB * kL;     //     524,288

  float* delta = (float*)ws;
  unsigned char* psi = (unsigned char*)(ws + deltaB);
  unsigned char* C = (unsigned char*)(ws + deltaB + psiB);
  int* E = (int*)(ws + deltaB + psiB + CBy);
  hipLaunchKernelGGL(fwd_delta, dim3(kB), dim3(512), 0, stream, feats, trans, delta);
  hipLaunchKernelGGL(psi_from_delta, dim3(16380), dim3(256), 0, stream, delta, trans, psi);
  hipLaunchKernelGGL(seg_compose, dim3(2048), dim3(256), 0, stream, psi, C);
  hipLaunchKernelGGL(score_scan, dim3(kB), dim3(64), 0, stream,
                     delta + (size_t)(kT - 1) * kB * kL, C, E, out);
  hipLaunchKernelGGL(path_fill, dim3(2048), dim3(256), 0, stream, psi, E, out);
}